// Round 10
// baseline (424.828 us; speedup 1.0000x reference)
//
#include <hip/hip_runtime.h>

#define N_NODES 100000
#define E_EDGES 1600000
#define EP (E_EDGES + N_NODES)
#define NG 1024
#define NEG 0.2f
#define EPS_BN 1e-5f
#define LOG2E 1.44269504088896f

#define NB 196        // dst buckets of 512 nodes
#define BCAP 12288    // per-bucket capacity (mean 8704)

typedef __attribute__((ext_vector_type(8))) short bf8_t;
typedef __attribute__((ext_vector_type(4))) float f4_t;

__device__ __forceinline__ unsigned short f2b(float f) {   // f32 -> bf16 RNE
    unsigned u = __float_as_uint(f);
    u += 0x7FFF + ((u >> 16) & 1);
    return (unsigned short)(u >> 16);
}

// 16-lane sum via mov_dpp row_ror butterfly; result broadcast to 16 lanes.
__device__ __forceinline__ float rsum16(float p) {
    p += __int_as_float(__builtin_amdgcn_mov_dpp(__float_as_int(p), 0x128, 0xf, 0xf, true));
    p += __int_as_float(__builtin_amdgcn_mov_dpp(__float_as_int(p), 0x124, 0xf, 0xf, true));
    p += __int_as_float(__builtin_amdgcn_mov_dpp(__float_as_int(p), 0x122, 0xf, 0xf, true));
    p += __int_as_float(__builtin_amdgcn_mov_dpp(__float_as_int(p), 0x121, 0xf, 0xf, true));
    return p;
}

// 4-lane (quad) sum via quad_perm DPP; result broadcast to all 4 lanes.
__device__ __forceinline__ float quadsum(float p) {
    p += __int_as_float(__builtin_amdgcn_mov_dpp(__float_as_int(p), 0xB1, 0xf, 0xf, true)); // [1,0,3,2]
    p += __int_as_float(__builtin_amdgcn_mov_dpp(__float_as_int(p), 0x4E, 0xf, 0xf, true)); // [2,3,0,1]
    return p;
}

// packed f32 math (VOP3P, CDNA2+). Non-volatile asm -> scheduler stays free.
__device__ __forceinline__ float2 pkadd(float2 a, float2 b) {
    float2 d;
    asm("v_pk_add_f32 %0, %1, %2" : "=v"(d) : "v"(a), "v"(b));
    return d;
}
__device__ __forceinline__ void pkfma(float2& c, float2 a, float2 b) {
    asm("v_pk_fma_f32 %0, %1, %2, %0" : "+v"(c) : "v"(a), "v"(b));
}

// ================= CSR build: partition -> per-bucket place (no global scan) =
__global__ __launch_bounds__(256) void k_part(const int* __restrict__ ei,
                                              int* __restrict__ bucketCur,
                                              int2* __restrict__ buf) {
    __shared__ int lh[NB], lb[NB];
    int t = threadIdx.x;
    for (int i = t; i < NB; i += 256) lh[i] = 0;
    __syncthreads();
    int base = blockIdx.x * 4096;
    int2 e[16];
    int rk[16];
#pragma unroll
    for (int i = 0; i < 16; i++) {
        int idx = base + i * 256 + t;
        int s, d;
        if (idx < E_EDGES) { s = ei[idx]; d = ei[E_EDGES + idx]; }
        else if (idx < EP) { s = d = idx - E_EDGES; }
        else { s = -1; d = -1; }
        e[i].x = s; e[i].y = d;
        rk[i] = (d >= 0) ? atomicAdd(&lh[d >> 9], 1) : 0;
    }
    __syncthreads();
    for (int i = t; i < NB; i += 256) lb[i] = atomicAdd(&bucketCur[i], lh[i]);
    __syncthreads();
#pragma unroll
    for (int i = 0; i < 16; i++) {
        int d = e[i].y;
        if (d >= 0) {
            int bkt = d >> 9;
            buf[(size_t)bkt * BCAP + lb[bkt] + rk[i]] = e[i];
        }
    }
}

// per-bucket histogram + LDS scan -> startA (bucket-local base) + cntA
__global__ __launch_bounds__(512) void k_build_a(const int2* __restrict__ buf,
                                                 const int* __restrict__ bcnt,
                                                 int* __restrict__ startA,
                                                 int* __restrict__ cntA) {
    __shared__ int h[512];
    __shared__ int s[512];
    int b = blockIdx.x, t = threadIdx.x;
    h[t] = 0;
    __syncthreads();
    int n = bcnt[b];
    const int2* p = buf + (size_t)b * BCAP;
    for (int i = t; i < n; i += 512) atomicAdd(&h[p[i].y & 511], 1);
    __syncthreads();
    int v = h[t];
    s[t] = v;
    __syncthreads();
    for (int o = 1; o < 512; o <<= 1) {
        int u = (t >= o) ? s[t - o] : 0;
        __syncthreads();
        s[t] += u;
        __syncthreads();
    }
    int node = (b << 9) + t;
    if (node < N_NODES) {
        startA[node] = b * BCAP + s[t] - v;   // exclusive prefix within bucket
        cntA[node] = v;
    }
}

// colA entries stored as BYTE offsets (src * 256) for direct gathers.
__global__ __launch_bounds__(256) void k_build_b(const int2* __restrict__ buf,
                                                 const int* __restrict__ bcnt,
                                                 const int* __restrict__ startA,
                                                 int* __restrict__ colA) {
    __shared__ int h[512];
    int b = blockIdx.x, t = threadIdx.x;
    for (int i = t; i < 512; i += 256) h[i] = 0;
    __syncthreads();
    int n = bcnt[b];
    const int2* p = buf + (size_t)b * BCAP;
    for (int i = t; i < n; i += 256) {
        int2 e = p[i];
        int r = atomicAdd(&h[e.y & 511], 1);
        colA[startA[e.y] + r] = e.x << 8;
    }
}

// ================= W preconvert: f32 [k][n] -> bf16 [mat][n][k] (linear) =====
__global__ void k_wconv(const float* __restrict__ Wl, const float* __restrict__ Wr,
                        unsigned short* __restrict__ img) {
    int g = blockIdx.x * 256 + threadIdx.x;   // 4096 chunks
    int m = g >> 11, n = (g >> 4) & 127, kb = g & 15;
    const float* W = m ? Wr : Wl;
    unsigned short v[8];
#pragma unroll
    for (int j = 0; j < 8; j++) v[j] = f2b(W[(kb * 8 + j) * 128 + n]);
    int off = m * 32768 + n * 256 + kb * 16;
    *(int4*)((char*)img + off) = *(int4*)v;
}

// ================= MFMA dual GEMM: xl = A@Wl + bl, xr = A@Wr + br (bf16) =====
// W fragments load straight from global (L2-hot) into VGPRs; LDS only for A
// tile (16KB swizzled) and the epilogue store bounce (32KB).
template<bool AFF, bool BF16IN>
__global__ __launch_bounds__(256) void k_gemm(
    const void* __restrict__ Ain, const unsigned short* __restrict__ Wimg,
    const float* __restrict__ bl, const float* __restrict__ br,
    const float* __restrict__ sc, const float* __restrict__ sh,
    unsigned short* __restrict__ xl, unsigned short* __restrict__ xr, int M)
{
    __shared__ char lds[32768];
    short* As = (short*)lds;             // 16384 B

    int t = threadIdx.x;
    int lane = t & 63;
    int w = t >> 6;
    int brow = blockIdx.x * 64;

    int rl = lane & 15;
    int kh = lane >> 4;
    int mat = w >> 1;
    int c0 = (w & 1) * 64;

    // ---- B fragments from global (issued first, overlap with A staging) ----
    const char* wbase = (const char*)Wimg + mat * 32768;
    bf8_t bfr[4][4];
#pragma unroll
    for (int s = 0; s < 4; ++s)
#pragma unroll
        for (int j = 0; j < 4; ++j)
            bfr[s][j] = *(const bf8_t*)(wbase + (c0 + 16 * j + rl) * 256 + s * 64 + kh * 16);

    // ---- stage A (f32 or packed-bf16 input; optional BN-affine+relu) ----
    {
        int kbase = (t & 7) * 16;
        float scv[16], shv[16];
        if (AFF) {
#pragma unroll
            for (int q = 0; q < 4; ++q) {
                float4 a4 = *(const float4*)&sc[kbase + q * 4];
                float4 b4 = *(const float4*)&sh[kbase + q * 4];
                scv[q*4+0]=a4.x; scv[q*4+1]=a4.y; scv[q*4+2]=a4.z; scv[q*4+3]=a4.w;
                shv[q*4+0]=b4.x; shv[q*4+1]=b4.y; shv[q*4+2]=b4.z; shv[q*4+3]=b4.w;
            }
        }
#pragma unroll
        for (int p = 0; p < 2; ++p) {
            int row = p * 32 + (t >> 3);
            int ar = brow + row; if (ar >= M) ar = M - 1;
            unsigned short vb[16];
            if (BF16IN) {
                const unsigned* src = (const unsigned*)Ain + (size_t)ar * 64 + (kbase >> 1);
                int4 r0 = *(const int4*)src;
                int4 r1 = *(const int4*)(src + 4);
                unsigned ua[8] = {(unsigned)r0.x,(unsigned)r0.y,(unsigned)r0.z,(unsigned)r0.w,
                                  (unsigned)r1.x,(unsigned)r1.y,(unsigned)r1.z,(unsigned)r1.w};
#pragma unroll
                for (int m = 0; m < 8; ++m) {
                    float f0 = __uint_as_float(ua[m] << 16);
                    float f1 = __uint_as_float(ua[m] & 0xFFFF0000u);
                    if (AFF) {
                        f0 = fmaxf(fmaf(f0, scv[2*m], shv[2*m]), 0.f);
                        f1 = fmaxf(fmaf(f1, scv[2*m+1], shv[2*m+1]), 0.f);
                    }
                    vb[2*m] = f2b(f0); vb[2*m+1] = f2b(f1);
                }
            } else {
                const float* src = (const float*)Ain + (size_t)ar * 128 + kbase;
#pragma unroll
                for (int q = 0; q < 4; ++q) {
                    float4 x4 = *(const float4*)&src[q * 4];
                    float vv[4] = {x4.x, x4.y, x4.z, x4.w};
#pragma unroll
                    for (int e = 0; e < 4; ++e) {
                        float f = vv[e];
                        if (AFF) f = fmaxf(fmaf(f, scv[q*4+e], shv[q*4+e]), 0.f);
                        vb[q * 4 + e] = f2b(f);
                    }
                }
            }
            int swz = (row & 7) << 4;
#pragma unroll
            for (int u = 0; u < 2; ++u) {
                int off = (row * 256 + kbase * 2 + u * 16) ^ swz;
                *(int4*)((char*)As + off) = *(int4*)&vb[u * 8];
            }
        }
    }
    __syncthreads();

    // ---- compute ----
    int swz = (rl & 7) << 4;
    f4_t acc[4][4];
#pragma unroll
    for (int i = 0; i < 4; ++i)
#pragma unroll
        for (int j = 0; j < 4; ++j) { f4_t z = {0.f,0.f,0.f,0.f}; acc[i][j] = z; }

    const char* Asc = (const char*)As;
#pragma unroll
    for (int s = 0; s < 4; ++s) {
        int kb2 = (s * 32 + kh * 8) * 2;
        bf8_t af[4];
#pragma unroll
        for (int i = 0; i < 4; ++i) {
            int row = 16 * i + rl;
            af[i] = *(const bf8_t*)(Asc + ((row * 256 + kb2) ^ swz));
        }
#pragma unroll
        for (int i = 0; i < 4; ++i)
#pragma unroll
            for (int j = 0; j < 4; ++j)
                acc[i][j] = __builtin_amdgcn_mfma_f32_16x16x32_bf16(af[i], bfr[s][j], acc[i][j], 0, 0, 0);
    }

    // ---- epilogue: bias + bf16, bounce through LDS for coalesced stores ----
    __syncthreads();
    short* Cs = (short*)lds;   // [64][256] bf16, swizzled (32 KB)
    const float* bb = mat ? br : bl;
    float blv[4];
#pragma unroll
    for (int j = 0; j < 4; ++j) blv[j] = bb[c0 + 16 * j + rl];
    int colbase = mat * 128 + c0;
#pragma unroll
    for (int i = 0; i < 4; ++i)
#pragma unroll
        for (int j = 0; j < 4; ++j) {
            int col = colbase + 16 * j + rl;
#pragma unroll
            for (int q = 0; q < 4; ++q) {
                int row = 16 * i + kh * 4 + q;
                int off = (row * 512 + col * 2) ^ ((row & 7) << 4);
                *(short*)((char*)Cs + off) = (short)f2b(acc[i][j][q] + blv[j]);
            }
        }
    __syncthreads();
#pragma unroll
    for (int rep = 0; rep < 8; ++rep) {
        int unit = rep * 256 + t;
        int row = unit >> 5;
        int slot = unit & 31;
        int gr = brow + row;
        if (gr < M) {
            int off = (row * 512 + slot * 16) ^ ((row & 7) << 4);
            int4 vv = *(const int4*)((char*)Cs + off);
            unsigned short* O = (slot < 16) ? xl : xr;
            int gcol = (slot & 15) * 8;
            *(int4*)&O[(size_t)gr * 128 + gcol] = vv;
        }
    }
}

// ===== per-node source logit precompute: Al[n][h] = 0.6*log2e * att_h . xl[n] =
__global__ __launch_bounds__(256) void k_adot(const unsigned* __restrict__ xl,
                                              const float* __restrict__ att,
                                              float* __restrict__ Al) {
    int lane = threadIdx.x & 63;
    int n = blockIdx.x * 4 + (threadIdx.x >> 6);
    int c0 = lane * 2;
    const float s = 0.6f * LOG2E;
    float a0 = att[c0] * s, a1 = att[c0 + 1] * s;
    unsigned u = xl[(size_t)n * 64 + lane];
    float v0 = __uint_as_float(u << 16);
    float v1 = __uint_as_float(u & 0xFFFF0000u);
    float p = fmaf(a0, v0, a1 * v1);
    p = rsum16(p);
    if ((lane & 15) == 0) Al[(size_t)n * 4 + (lane >> 4)] = p;
}

// ===== fused edge softmax + aggregation, lane = (edge, head, quarter) ========
// 2x-unrolled, register-refill pipeline (no rotation moves), packed-f32 math.
__global__ __launch_bounds__(256) void k_agg(
    const unsigned* __restrict__ xl, const unsigned* __restrict__ xr,
    const int* __restrict__ startA, const int* __restrict__ cntA,
    const unsigned* __restrict__ colB,
    const float* __restrict__ att, const float* __restrict__ bias,
    const float* __restrict__ Al, unsigned* __restrict__ hout)
{
    int tid = threadIdx.x;
    int lane = tid & 63;
    int n = blockIdx.x * 4 + (tid >> 6);
    int e = lane >> 4;                 // edge slot 0..3
    int hq = lane & 15;                // h*4+q
    int h4 = (hq >> 2) * 4;            // byte offset of head in Al row
    unsigned hq16 = (unsigned)hq * 16u;
    const char* xlb = (const char*)xl;
    const char* alb = (const char*)Al;

    // att' slice (8 ch of this head-quarter), pre-scaled by 0.4*log2e
    float2 ap2[4];
    {
        float4 q0 = *(const float4*)&att[hq * 8];
        float4 q1 = *(const float4*)&att[hq * 8 + 4];
        const float s = 0.4f * LOG2E;
        ap2[0] = make_float2(q0.x*s, q0.y*s);
        ap2[1] = make_float2(q0.z*s, q0.w*s);
        ap2[2] = make_float2(q1.x*s, q1.y*s);
        ap2[3] = make_float2(q1.z*s, q1.w*s);
    }
    // xr slice for this node
    float2 zx2[4];
    {
        int4 xru = *(const int4*)((const char*)xr + (size_t)n * 256 + hq16);
        unsigned ua = (unsigned)xru.x, ub = (unsigned)xru.y;
        unsigned uc = (unsigned)xru.z, ud = (unsigned)xru.w;
        zx2[0] = make_float2(__uint_as_float(ua << 16), __uint_as_float(ua & 0xFFFF0000u));
        zx2[1] = make_float2(__uint_as_float(ub << 16), __uint_as_float(ub & 0xFFFF0000u));
        zx2[2] = make_float2(__uint_as_float(uc << 16), __uint_as_float(uc & 0xFFFF0000u));
        zx2[3] = make_float2(__uint_as_float(ud << 16), __uint_as_float(ud & 0xFFFF0000u));
    }
    // Snode = 0.6*log2e * att_h . xr[n]  (= 1.5 * quadsum(dot(ap, zx)))
    float arp = ap2[0].x * zx2[0].x;
    arp = fmaf(ap2[0].y, zx2[0].y, arp);
#pragma unroll
    for (int k = 1; k < 4; ++k) {
        arp = fmaf(ap2[k].x, zx2[k].x, arp);
        arp = fmaf(ap2[k].y, zx2[k].y, arp);
    }
    float Snode = 1.5f * quadsum(arp);

    int a0i = startA[n];
    int cn = cntA[n];                  // >= 1 (self loop)
    int nb = (cn + 3) >> 2;

    // prologue: data for blocks 0,1; lookahead offsets for blocks 2,3
    // (colA gaps are zeroed -> stray reads hit node 0, masked out by wg)
    unsigned o0 = colB[a0i + e];
    unsigned o1 = colB[a0i + 4 + e];
    unsigned oA = colB[a0i + 8 + e];
    unsigned oB = colB[a0i + 12 + e];
    int4 d0 = *(const int4*)(xlb + o0 + hq16);
    float al0v = *(const float*)(alb + ((o0 >> 4) & ~15u) + h4);
    int4 d1 = *(const int4*)(xlb + o1 + hq16);
    float al1v = *(const float*)(alb + ((o1 >> 4) & ~15u) + h4);

    float2 acc2[4] = {{0.f,0.f},{0.f,0.f},{0.f,0.f},{0.f,0.f}};
    float wsum = 0.f;

#define COMPUTE(D, ALV, BLK)                                                   \
    {                                                                          \
        unsigned ua = (unsigned)(D).x, ub = (unsigned)(D).y;                   \
        unsigned uc = (unsigned)(D).z, ud = (unsigned)(D).w;                   \
        float2 z0 = make_float2(__uint_as_float(ua << 16), __uint_as_float(ua & 0xFFFF0000u)); \
        float2 z1 = make_float2(__uint_as_float(ub << 16), __uint_as_float(ub & 0xFFFF0000u)); \
        float2 z2 = make_float2(__uint_as_float(uc << 16), __uint_as_float(uc & 0xFFFF0000u)); \
        float2 z3 = make_float2(__uint_as_float(ud << 16), __uint_as_float(ud & 0xFFFF0000u)); \
        float2 t0 = pkadd(z0, zx2[0]);                                         \
        float2 t1 = pkadd(z1, zx2[1]);                                         \
        float2 t2 = pkadd(z2, zx2[2]);                                         \
        float2 t3 = pkadd(z3, zx2[3]);                                         \
        float Dd = ap2[0].x * fabsf(t0.x);                                     \
        Dd = fmaf(ap2[0].y, fabsf(t0.y), Dd);                                  \
        Dd = fmaf(ap2[1].x, fabsf(t1.x), Dd);                                  \
        Dd = fmaf(ap2[1].y, fabsf(t1.y), Dd);                                  \
        Dd = fmaf(ap2[2].x, fabsf(t2.x), Dd);                                  \
        Dd = fmaf(ap2[2].y, fabsf(t2.y), Dd);                                  \
        Dd = fmaf(ap2[3].x, fabsf(t3.x), Dd);                                  \
        Dd = fmaf(ap2[3].y, fabsf(t3.y), Dd);                                  \
        Dd = quadsum(Dd);                                                      \
        float wg = exp2f((ALV) + Snode + Dd);                                  \
        wg = ((BLK) * 4 + e < cn) ? wg : 0.f;                                  \
        float2 wg2 = make_float2(wg, wg);                                      \
        pkfma(acc2[0], z0, wg2);                                               \
        pkfma(acc2[1], z1, wg2);                                               \
        pkfma(acc2[2], z2, wg2);                                               \
        pkfma(acc2[3], z3, wg2);                                               \
        wsum += wg;                                                            \
    }

    int b = 0;
    for (; b + 2 <= nb; b += 2) {
        COMPUTE(d0, al0v, b);
        d0 = *(const int4*)(xlb + oA + hq16);
        al0v = *(const float*)(alb + ((oA >> 4) & ~15u) + h4);
        oA = colB[a0i + (b + 4) * 4 + e];
        COMPUTE(d1, al1v, b + 1);
        d1 = *(const int4*)(xlb + oB + hq16);
        al1v = *(const float*)(alb + ((oB >> 4) & ~15u) + h4);
        oB = colB[a0i + (b + 5) * 4 + e];
    }
    if (b < nb) COMPUTE(d0, al0v, b);
#undef COMPUTE

    // reduce across the 4 edge groups (lanes xor 16, 32)
#pragma unroll
    for (int k = 0; k < 4; ++k) {
        acc2[k].x += __shfl_xor(acc2[k].x, 16, 64);
        acc2[k].x += __shfl_xor(acc2[k].x, 32, 64);
        acc2[k].y += __shfl_xor(acc2[k].y, 16, 64);
        acc2[k].y += __shfl_xor(acc2[k].y, 32, 64);
    }
    wsum += __shfl_xor(wsum, 16, 64);
    wsum += __shfl_xor(wsum, 32, 64);

    float inv = 1.f / wsum;
    float4 b0 = *(const float4*)&bias[hq * 8];
    float4 b1 = *(const float4*)&bias[hq * 8 + 4];
    float bv[8] = {b0.x,b0.y,b0.z,b0.w,b1.x,b1.y,b1.z,b1.w};
    float av[8] = {acc2[0].x,acc2[0].y,acc2[1].x,acc2[1].y,
                   acc2[2].x,acc2[2].y,acc2[3].x,acc2[3].y};
    unsigned r[4];
#pragma unroll
    for (int k = 0; k < 4; ++k) {
        float o0f = fmaf(av[2*k],     inv, bv[2*k]);
        float o1f = fmaf(av[2*k + 1], inv, bv[2*k + 1]);
        r[k] = (unsigned)f2b(o0f) | ((unsigned)f2b(o1f) << 16);
    }
    if (lane < 16)
        *(int4*)((char*)hout + (size_t)n * 256 + hq16) = *(int4*)r;
}

// ================= BatchNorm stats (bf16 h) + finalize =======================
__global__ __launch_bounds__(256) void k_bnstats(const unsigned* __restrict__ h,
                                                 float* __restrict__ gsum,
                                                 float* __restrict__ gsq) {
    int t = threadIdx.x;
    int col = t & 63;
    int wv = t >> 6;
    float s0 = 0.f, s1 = 0.f, q0 = 0.f, q1 = 0.f;
    for (int r = blockIdx.x * 4 + wv; r < N_NODES; r += 512 * 4) {
        unsigned u = h[(size_t)r * 64 + col];
        float v0 = __uint_as_float(u << 16);
        float v1 = __uint_as_float(u & 0xFFFF0000u);
        s0 += v0; q0 = fmaf(v0, v0, q0);
        s1 += v1; q1 = fmaf(v1, v1, q1);
    }
    __shared__ float2 sS[4][64], sQ[4][64];
    sS[wv][col] = make_float2(s0, s1);
    sQ[wv][col] = make_float2(q0, q1);
    __syncthreads();
    if (t < 64) {
        float2 a0 = sS[0][t], a1 = sS[1][t], a2 = sS[2][t], a3 = sS[3][t];
        float2 b0 = sQ[0][t], b1 = sQ[1][t], b2 = sQ[2][t], b3 = sQ[3][t];
        atomicAdd(&gsum[2 * t],     a0.x + a1.x + a2.x + a3.x);
        atomicAdd(&gsum[2 * t + 1], a0.y + a1.y + a2.y + a3.y);
        atomicAdd(&gsq[2 * t],      b0.x + b1.x + b2.x + b3.x);
        atomicAdd(&gsq[2 * t + 1],  b0.y + b1.y + b2.y + b3.y);
    }
}

__global__ void k_bnfinal(const float* __restrict__ gsum, const float* __restrict__ gsq,
                          const float* __restrict__ g, const float* __restrict__ be,
                          float* __restrict__ sc, float* __restrict__ sh) {
    int c = threadIdx.x;   // 128
    float mu = gsum[c] * (1.f / N_NODES);
    float var = gsq[c] * (1.f / N_NODES) - mu * mu;
    float s = rsqrtf(var + EPS_BN) * g[c];
    sc[c] = s;
    sh[c] = be[c] - mu * s;
}

// ================= graph boundaries (batch is sorted) ========================
__global__ void k_gstart(const int* __restrict__ batch, int* __restrict__ gstart) {
    int i = blockIdx.x * 256 + threadIdx.x;
    if (i >= N_NODES) return;
    int b = batch[i];
    int prev = (i == 0) ? -1 : batch[i - 1];
    for (int g = prev + 1; g <= b; g++) gstart[g] = i;
    if (i == N_NODES - 1)
        for (int g = b + 1; g <= NG; g++) gstart[g] = N_NODES;
}

// ====== mean pool over bf16 h (fused BN2 affine+relu) + concat global =======
__global__ __launch_bounds__(256) void k_pool(const unsigned* __restrict__ h,
                                              const int* __restrict__ gstart,
                                              const float* __restrict__ gf,
                                              const float* __restrict__ sc,
                                              const float* __restrict__ sh,
                                              float* __restrict__ z) {
    int wave = threadIdx.x >> 6;
    int lane = threadIdx.x & 63;
    int g = blockIdx.x * 4 + wave;
    if (g >= NG) return;
    int c0 = lane * 2;
    float sc0 = sc[c0], sc1 = sc[c0 + 1], sh0 = sh[c0], sh1 = sh[c0 + 1];
    int r0 = gstart[g], r1 = gstart[g + 1];
    float s0 = 0.f, s1 = 0.f;
    for (int r = r0; r < r1; r++) {
        unsigned u = h[(size_t)r * 64 + lane];
        float v0 = __uint_as_float(u << 16);
        float v1 = __uint_as_float(u & 0xFFFF0000u);
        s0 += fmaxf(fmaf(v0, sc0, sh0), 0.f);
        s1 += fmaxf(fmaf(v1, sc1, sh1), 0.f);
    }
    float invc = 1.f / fmaxf((float)(r1 - r0), 1.f);
    float2 o; o.x = s0 * invc; o.y = s1 * invc;
    *(float2*)&z[(size_t)g * 160 + c0] = o;
    if (lane < 16) {
        float2 gv = *(const float2*)&gf[(size_t)g * 32 + lane * 2];
        *(float2*)&z[(size_t)g * 160 + 128 + lane * 2] = gv;
    }
}

// ================= MLP head ==================================================
__global__ __launch_bounds__(256) void k_mlp(const float* __restrict__ z,
                                             const float* __restrict__ W1,
                                             const float* __restrict__ b1,
                                             const float* __restrict__ W2,
                                             const float* __restrict__ b2,
                                             float* __restrict__ out) {
    __shared__ float zs[160];
    __shared__ float red[4];
    int g = blockIdx.x;
    int t = threadIdx.x;
    if (t < 160) zs[t] = z[(size_t)g * 160 + t];
    __syncthreads();
    float acc = b1[t];
#pragma unroll 8
    for (int i = 0; i < 160; i++) acc = fmaf(zs[i], W1[i * 256 + t], acc);
    acc = fmaxf(acc, 0.f);
    float part = acc * W2[t];
    part += __shfl_xor(part, 32, 64);
    part += __shfl_xor(part, 16, 64);
    part += __shfl_xor(part, 8, 64);
    part += __shfl_xor(part, 4, 64);
    part += __shfl_xor(part, 2, 64);
    part += __shfl_xor(part, 1, 64);
    if ((t & 63) == 0) red[t >> 6] = part;
    __syncthreads();
    if (t == 0) out[g] = red[0] + red[1] + red[2] + red[3] + b2[0];
}

extern "C" void kernel_launch(void* const* d_in, const int* in_sizes, int n_in,
                              void* d_out, int out_size, void* d_ws, size_t ws_size,
                              hipStream_t stream) {
    (void)in_sizes; (void)n_in; (void)out_size; (void)ws_size;

    const float* x     = (const float*)d_in[0];
    const int*   ei    = (const int*)d_in[1];
    const int*   batch = (const int*)d_in[2];
    const float* gf    = (const float*)d_in[3];
    const float* Wl1 = (const float*)d_in[4];
    const float* bl1 = (const float*)d_in[5];
    const float* Wr1 = (const float*)d_in[6];
    const float* br1 = (const float*)d_in[7];
    const float* att1  = (const float*)d_in[8];
    const float* bias1 = (const float*)d_in[9];
    const float* g1  = (const float*)d_in[10];
    const float* be1 = (const float*)d_in[11];
    const float* Wl2 = (const float*)d_in[12];
    const float* bl2 = (const float*)d_in[13];
    const float* Wr2 = (const float*)d_in[14];
    const float* br2 = (const float*)d_in[15];
    const float* att2  = (const float*)d_in[16];
    const float* bias2 = (const float*)d_in[17];
    const float* g2  = (const float*)d_in[18];
    const float* be2 = (const float*)d_in[19];
    const float* Wfc1 = (const float*)d_in[20];
    const float* bfc1 = (const float*)d_in[21];
    const float* Wfc2 = (const float*)d_in[22];
    const float* bfc2 = (const float*)d_in[23];
    float* out = (float*)d_out;

    char* ws = (char*)d_ws;
    unsigned short* xl = (unsigned short*)(ws + 0);            // 25.6 MB bf16
    unsigned short* xr = (unsigned short*)(ws + 25600000);     // 25.6 MB bf16
    unsigned* h     = (unsigned*)(ws + 51200000);              // 25.6 MB bf16 packed
    int*   colA     = (int*)(ws + 76800000);                   // 9.63 MB (bucketed, zeroed)
    int2*  bktBuf   = (int2*)(ws + 86434816);                  // 19.27 MB
    int*   bucketCur= (int*)(ws + 105702400);                  // 1 KB   } zeroed
    float* bnsum    = (float*)(ws + 105703424);                // 2 KB   } together
    int*   cntA     = (int*)(ws + 105705472);                  // 400 KB
    int*   startA   = (int*)(ws + 106105472);                  // 400 KB
    float* scsh     = (float*)(ws + 106505472);                // sc1|sh1|sc2|sh2
    int*   gstart   = (int*)(ws + 106507520);                  // 4.1 KB
    float* z        = (float*)(ws + 106511872);                // 655 KB
    unsigned short* Wimg = (unsigned short*)(ws + 107167232);  // 64 KB
    float* Al       = (float*)(ws + 107232768);                // 1.6 MB [N][4]

    // zero: colA (gap entries must be 0 -> safe stray gathers), bucketCur+bnsum
    hipMemsetAsync(colA, 0, NB * BCAP * 4, stream);
    hipMemsetAsync(bucketCur, 0, 1024 + 2048, stream);

    // CSR build (shared by both layers) + graph boundaries
    k_part<<<(EP + 4095) / 4096, 256, 0, stream>>>(ei, bucketCur, bktBuf);
    k_gstart<<<(N_NODES + 255) / 256, 256, 0, stream>>>(batch, gstart);
    k_build_a<<<NB, 512, 0, stream>>>(bktBuf, bucketCur, startA, cntA);
    k_build_b<<<NB, 256, 0, stream>>>(bktBuf, bucketCur, startA, colA);

    int gemm_grid = (N_NODES + 63) / 64;

    // Layer 1
    k_wconv<<<16, 256, 0, stream>>>(Wl1, Wr1, Wimg);
    k_gemm<false, false><<<gemm_grid, 256, 0, stream>>>(x, Wimg, bl1, br1,
                                                        nullptr, nullptr, xl, xr, N_NODES);
    k_adot<<<N_NODES / 4, 256, 0, stream>>>((const unsigned*)xl, att1, Al);
    k_agg<<<N_NODES / 4, 256, 0, stream>>>((const unsigned*)xl, (const unsigned*)xr,
                                           startA, cntA, (const unsigned*)colA,
                                           att1, bias1, Al, h);
    k_bnstats<<<512, 256, 0, stream>>>(h, bnsum + 0, bnsum + 128);
    k_bnfinal<<<1, 128, 0, stream>>>(bnsum + 0, bnsum + 128, g1, be1, scsh + 0, scsh + 128);

    // Layer 2 (BN1 apply + ReLU fused into GEMM A-staging, bf16 input)
    k_wconv<<<16, 256, 0, stream>>>(Wl2, Wr2, Wimg);
    k_gemm<true, true><<<gemm_grid, 256, 0, stream>>>(h, Wimg, bl2, br2,
                                                      scsh + 0, scsh + 128, xl, xr, N_NODES);
    k_adot<<<N_NODES / 4, 256, 0, stream>>>((const unsigned*)xl, att2, Al);
    k_agg<<<N_NODES / 4, 256, 0, stream>>>((const unsigned*)xl, (const unsigned*)xr,
                                           startA, cntA, (const unsigned*)colA,
                                           att2, bias2, Al, h);
    k_bnstats<<<512, 256, 0, stream>>>(h, bnsum + 256, bnsum + 384);
    k_bnfinal<<<1, 128, 0, stream>>>(bnsum + 256, bnsum + 384, g2, be2, scsh + 256, scsh + 384);

    // Pool (BN2 apply + ReLU fused) + MLP
    k_pool<<<(NG + 3) / 4, 256, 0, stream>>>(h, gstart, gf, scsh + 256, scsh + 384, z);
    k_mlp<<<NG, 256, 0, stream>>>(z, Wfc1, bfc1, Wfc2, bfc2, out);
}

// Round 11
// 406.166 us; speedup vs baseline: 1.0459x; 1.0459x over previous
//
#include <hip/hip_runtime.h>

#define N_NODES 100000
#define E_EDGES 1600000
#define EP (E_EDGES + N_NODES)
#define NG 1024
#define NEG 0.2f
#define EPS_BN 1e-5f
#define LOG2E 1.44269504088896f

#define NB 196        // dst buckets of 512 nodes
#define BCAP 12288    // per-bucket capacity (mean 8704)

typedef __attribute__((ext_vector_type(8))) short bf8_t;
typedef __attribute__((ext_vector_type(4))) float f4_t;

__device__ __forceinline__ unsigned short f2b(float f) {   // f32 -> bf16 RNE
    unsigned u = __float_as_uint(f);
    u += 0x7FFF + ((u >> 16) & 1);
    return (unsigned short)(u >> 16);
}

// 16-lane sum via mov_dpp row_ror butterfly; result broadcast to 16 lanes.
__device__ __forceinline__ float rsum16(float p) {
    p += __int_as_float(__builtin_amdgcn_mov_dpp(__float_as_int(p), 0x128, 0xf, 0xf, true));
    p += __int_as_float(__builtin_amdgcn_mov_dpp(__float_as_int(p), 0x124, 0xf, 0xf, true));
    p += __int_as_float(__builtin_amdgcn_mov_dpp(__float_as_int(p), 0x122, 0xf, 0xf, true));
    p += __int_as_float(__builtin_amdgcn_mov_dpp(__float_as_int(p), 0x121, 0xf, 0xf, true));
    return p;
}

// 4-lane (quad) sum via quad_perm DPP; result broadcast to all 4 lanes.
__device__ __forceinline__ float quadsum(float p) {
    p += __int_as_float(__builtin_amdgcn_mov_dpp(__float_as_int(p), 0xB1, 0xf, 0xf, true)); // [1,0,3,2]
    p += __int_as_float(__builtin_amdgcn_mov_dpp(__float_as_int(p), 0x4E, 0xf, 0xf, true)); // [2,3,0,1]
    return p;
}

__device__ __forceinline__ void unpack8(const int4& d, float* z) {
    unsigned a = (unsigned)d.x, b = (unsigned)d.y, c = (unsigned)d.z, w = (unsigned)d.w;
    z[0] = __uint_as_float(a << 16); z[1] = __uint_as_float(a & 0xFFFF0000u);
    z[2] = __uint_as_float(b << 16); z[3] = __uint_as_float(b & 0xFFFF0000u);
    z[4] = __uint_as_float(c << 16); z[5] = __uint_as_float(c & 0xFFFF0000u);
    z[6] = __uint_as_float(w << 16); z[7] = __uint_as_float(w & 0xFFFF0000u);
}

// ================= CSR build: partition -> per-bucket build (packed int) =====
// buf entry = (src << 9) | (dst & 511); bucket = dst >> 9.
__global__ __launch_bounds__(256) void k_part(const int* __restrict__ ei,
                                              int* __restrict__ bucketCur,
                                              int* __restrict__ buf) {
    __shared__ int lh[NB], lb[NB];
    int t = threadIdx.x;
    for (int i = t; i < NB; i += 256) lh[i] = 0;
    __syncthreads();
    int base = blockIdx.x * 4096;
    int pk[16];
    int bk[16];
    int rk[16];
#pragma unroll
    for (int i = 0; i < 16; i++) {
        int idx = base + i * 256 + t;
        int s, d;
        if (idx < E_EDGES) { s = ei[idx]; d = ei[E_EDGES + idx]; }
        else if (idx < EP) { s = d = idx - E_EDGES; }
        else { s = 0; d = -1; }
        pk[i] = (s << 9) | (d & 511);
        bk[i] = d >> 9;
        rk[i] = (d >= 0) ? atomicAdd(&lh[d >> 9], 1) : 0;
    }
    __syncthreads();
    for (int i = t; i < NB; i += 256) lb[i] = atomicAdd(&bucketCur[i], lh[i]);
    __syncthreads();
#pragma unroll
    for (int i = 0; i < 16; i++) {
        int bkt = bk[i];
        if (bkt >= 0)
            buf[(size_t)bkt * BCAP + lb[bkt] + rk[i]] = pk[i];
    }
}

// per-bucket: histogram -> LDS scan -> startA/cntA -> place colA (byte offsets)
__global__ __launch_bounds__(512) void k_build(const int* __restrict__ buf,
                                               const int* __restrict__ bcnt,
                                               int* __restrict__ startA,
                                               int* __restrict__ cntA,
                                               int* __restrict__ colA) {
    __shared__ int h[512];
    __shared__ int s[512];
    int b = blockIdx.x, t = threadIdx.x;
    h[t] = 0;
    __syncthreads();
    int n = bcnt[b];
    const int* p = buf + (size_t)b * BCAP;
    for (int i = t; i < n; i += 512) atomicAdd(&h[p[i] & 511], 1);
    __syncthreads();
    int v = h[t];
    s[t] = v;
    __syncthreads();
    for (int o = 1; o < 512; o <<= 1) {
        int u = (t >= o) ? s[t - o] : 0;
        __syncthreads();
        s[t] += u;
        __syncthreads();
    }
    int myStart = b * BCAP + s[t] - v;   // exclusive prefix within bucket
    int node = (b << 9) + t;
    if (node < N_NODES) {
        startA[node] = myStart;
        cntA[node] = v;
    }
    h[t] = myStart;                      // reuse as running cursor
    __syncthreads();
    for (int i = t; i < n; i += 512) {
        int e = p[i];
        int r = atomicAdd(&h[e & 511], 1);
        colA[r] = (e >> 9) << 8;         // src * 256 (byte offset into xl)
    }
}

// ================= W preconvert: f32 [k][n] -> bf16 [mat][n][k] (linear) =====
__global__ void k_wconv(const float* __restrict__ Wl, const float* __restrict__ Wr,
                        unsigned short* __restrict__ img) {
    int g = blockIdx.x * 256 + threadIdx.x;   // 4096 chunks
    int m = g >> 11, n = (g >> 4) & 127, kb = g & 15;
    const float* W = m ? Wr : Wl;
    unsigned short v[8];
#pragma unroll
    for (int j = 0; j < 8; j++) v[j] = f2b(W[(kb * 8 + j) * 128 + n]);
    int off = m * 32768 + n * 256 + kb * 16;
    *(int4*)((char*)img + off) = *(int4*)v;
}

// ================= MFMA dual GEMM: xl = A@Wl + bl, xr = A@Wr + br (bf16) =====
// W fragments straight from global (L2-hot). Fused epilogue also emits
// Al[n][h] = 0.6*log2e * att_h . xl[n]  (from f32 accumulators, mat=0 waves).
template<bool AFF, bool BF16IN>
__global__ __launch_bounds__(256) void k_gemm(
    const void* __restrict__ Ain, const unsigned short* __restrict__ Wimg,
    const float* __restrict__ bl, const float* __restrict__ br,
    const float* __restrict__ sc, const float* __restrict__ sh,
    const float* __restrict__ att, float* __restrict__ Al,
    unsigned short* __restrict__ xl, unsigned short* __restrict__ xr, int M)
{
    __shared__ char lds[32768];
    short* As = (short*)lds;             // 16384 B

    int t = threadIdx.x;
    int lane = t & 63;
    int w = t >> 6;
    int brow = blockIdx.x * 64;

    int rl = lane & 15;
    int kh = lane >> 4;
    int mat = w >> 1;
    int c0 = (w & 1) * 64;

    // ---- B fragments from global (issued first, overlap with A staging) ----
    const char* wbase = (const char*)Wimg + mat * 32768;
    bf8_t bfr[4][4];
#pragma unroll
    for (int s = 0; s < 4; ++s)
#pragma unroll
        for (int j = 0; j < 4; ++j)
            bfr[s][j] = *(const bf8_t*)(wbase + (c0 + 16 * j + rl) * 256 + s * 64 + kh * 16);

    // ---- stage A (f32 or packed-bf16 input; optional BN-affine+relu) ----
    {
        int kbase = (t & 7) * 16;
        float scv[16], shv[16];
        if (AFF) {
#pragma unroll
            for (int q = 0; q < 4; ++q) {
                float4 a4 = *(const float4*)&sc[kbase + q * 4];
                float4 b4 = *(const float4*)&sh[kbase + q * 4];
                scv[q*4+0]=a4.x; scv[q*4+1]=a4.y; scv[q*4+2]=a4.z; scv[q*4+3]=a4.w;
                shv[q*4+0]=b4.x; shv[q*4+1]=b4.y; shv[q*4+2]=b4.z; shv[q*4+3]=b4.w;
            }
        }
#pragma unroll
        for (int p = 0; p < 2; ++p) {
            int row = p * 32 + (t >> 3);
            int ar = brow + row; if (ar >= M) ar = M - 1;
            unsigned short vb[16];
            if (BF16IN) {
                const unsigned* src = (const unsigned*)Ain + (size_t)ar * 64 + (kbase >> 1);
                int4 r0 = *(const int4*)src;
                int4 r1 = *(const int4*)(src + 4);
                unsigned ua[8] = {(unsigned)r0.x,(unsigned)r0.y,(unsigned)r0.z,(unsigned)r0.w,
                                  (unsigned)r1.x,(unsigned)r1.y,(unsigned)r1.z,(unsigned)r1.w};
#pragma unroll
                for (int m = 0; m < 8; ++m) {
                    float f0 = __uint_as_float(ua[m] << 16);
                    float f1 = __uint_as_float(ua[m] & 0xFFFF0000u);
                    if (AFF) {
                        f0 = fmaxf(fmaf(f0, scv[2*m], shv[2*m]), 0.f);
                        f1 = fmaxf(fmaf(f1, scv[2*m+1], shv[2*m+1]), 0.f);
                    }
                    vb[2*m] = f2b(f0); vb[2*m+1] = f2b(f1);
                }
            } else {
                const float* src = (const float*)Ain + (size_t)ar * 128 + kbase;
#pragma unroll
                for (int q = 0; q < 4; ++q) {
                    float4 x4 = *(const float4*)&src[q * 4];
                    float vv[4] = {x4.x, x4.y, x4.z, x4.w};
#pragma unroll
                    for (int e = 0; e < 4; ++e) {
                        float f = vv[e];
                        if (AFF) f = fmaxf(fmaf(f, scv[q*4+e], shv[q*4+e]), 0.f);
                        vb[q * 4 + e] = f2b(f);
                    }
                }
            }
            int swz = (row & 7) << 4;
#pragma unroll
            for (int u = 0; u < 2; ++u) {
                int off = (row * 256 + kbase * 2 + u * 16) ^ swz;
                *(int4*)((char*)As + off) = *(int4*)&vb[u * 8];
            }
        }
    }
    __syncthreads();

    // ---- compute ----
    int swz = (rl & 7) << 4;
    f4_t acc[4][4];
#pragma unroll
    for (int i = 0; i < 4; ++i)
#pragma unroll
        for (int j = 0; j < 4; ++j) { f4_t z = {0.f,0.f,0.f,0.f}; acc[i][j] = z; }

    const char* Asc = (const char*)As;
#pragma unroll
    for (int s = 0; s < 4; ++s) {
        int kb2 = (s * 32 + kh * 8) * 2;
        bf8_t af[4];
#pragma unroll
        for (int i = 0; i < 4; ++i) {
            int row = 16 * i + rl;
            af[i] = *(const bf8_t*)(Asc + ((row * 256 + kb2) ^ swz));
        }
#pragma unroll
        for (int i = 0; i < 4; ++i)
#pragma unroll
            for (int j = 0; j < 4; ++j)
                acc[i][j] = __builtin_amdgcn_mfma_f32_16x16x32_bf16(af[i], bfr[s][j], acc[i][j], 0, 0, 0);
    }

    // ---- epilogue ----
    __syncthreads();
    short* Cs = (short*)lds;   // [64][256] bf16, swizzled (32 KB)
    const float* bb = mat ? br : bl;
    float blv[4];
#pragma unroll
    for (int j = 0; j < 4; ++j) blv[j] = bb[c0 + 16 * j + rl];

    // fused Al (source-logit) for xl waves: per-head 32-ch dot via rsum16.
    if (mat == 0) {
        const float sAl = 0.6f * LOG2E;
        float ap0 = att[c0 + rl] * sAl;
        float ap1 = att[c0 + 16 + rl] * sAl;
        float ap2 = att[c0 + 32 + rl] * sAl;
        float ap3 = att[c0 + 48 + rl] * sAl;
        float cl = fmaf(ap0, blv[0], ap1 * blv[1]);
        float ch = fmaf(ap2, blv[2], ap3 * blv[3]);
        int hbase = c0 >> 5;   // 0 (w=0) or 2 (w=1)
#pragma unroll
        for (int i = 0; i < 4; ++i)
#pragma unroll
            for (int q = 0; q < 4; ++q) {
                float pl = fmaf(ap0, acc[i][0][q], fmaf(ap1, acc[i][1][q], cl));
                float ph = fmaf(ap2, acc[i][2][q], fmaf(ap3, acc[i][3][q], ch));
                pl = rsum16(pl);
                ph = rsum16(ph);
                int node = brow + 16 * i + kh * 4 + q;
                if (rl == 0 && node < M) {
                    float2 w2 = make_float2(pl, ph);
                    *(float2*)&Al[(size_t)node * 4 + hbase] = w2;
                }
            }
    }

#pragma unroll
    for (int i = 0; i < 4; ++i)
#pragma unroll
        for (int j = 0; j < 4; ++j) {
            int col = mat * 128 + c0 + 16 * j + rl;
#pragma unroll
            for (int q = 0; q < 4; ++q) {
                int row = 16 * i + kh * 4 + q;
                int off = (row * 512 + col * 2) ^ ((row & 7) << 4);
                *(short*)((char*)Cs + off) = (short)f2b(acc[i][j][q] + blv[j]);
            }
        }
    __syncthreads();
#pragma unroll
    for (int rep = 0; rep < 8; ++rep) {
        int unit = rep * 256 + t;
        int row = unit >> 5;
        int slot = unit & 31;
        int gr = brow + row;
        if (gr < M) {
            int off = (row * 512 + slot * 16) ^ ((row & 7) << 4);
            int4 vv = *(const int4*)((char*)Cs + off);
            unsigned short* O = (slot < 16) ? xl : xr;
            int gcol = (slot & 15) * 8;
            *(int4*)&O[(size_t)gr * 128 + gcol] = vv;
        }
    }
}

// ===== fused edge softmax + aggregation, lane = (edge, head, quarter) ========
// round-7 structure: rotation pipeline depth 2 blocks, plain fma/abs math.
__global__ __launch_bounds__(256) void k_agg(
    const unsigned* __restrict__ xl, const unsigned* __restrict__ xr,
    const int* __restrict__ startA, const int* __restrict__ cntA,
    const unsigned* __restrict__ colB,
    const float* __restrict__ att, const float* __restrict__ bias,
    const float* __restrict__ Al, unsigned* __restrict__ hout)
{
    int tid = threadIdx.x;
    int lane = tid & 63;
    int n = blockIdx.x * 4 + (tid >> 6);
    int e = lane >> 4;                 // edge slot 0..3
    int hq = lane & 15;                // h*4+q
    int h4 = (hq >> 2) * 4;            // byte offset of head in Al row
    unsigned hq16 = (unsigned)hq * 16u;
    const char* xlb = (const char*)xl;
    const char* alb = (const char*)Al;

    // att' slice (8 ch of this head-quarter), pre-scaled by 0.4*log2e
    float ap[8];
    {
        float4 q0 = *(const float4*)&att[hq * 8];
        float4 q1 = *(const float4*)&att[hq * 8 + 4];
        const float s = 0.4f * LOG2E;
        ap[0]=q0.x*s; ap[1]=q0.y*s; ap[2]=q0.z*s; ap[3]=q0.w*s;
        ap[4]=q1.x*s; ap[5]=q1.y*s; ap[6]=q1.z*s; ap[7]=q1.w*s;
    }
    // xr slice for this node
    float zx[8];
    {
        int4 xru = *(const int4*)((const char*)xr + (size_t)n * 256 + hq16);
        unpack8(xru, zx);
    }
    // Snode = 0.6*log2e * att_h . xr[n]  (= 1.5 * quadsum(dot(ap, zx)))
    float arp = ap[0] * zx[0];
#pragma unroll
    for (int c = 1; c < 8; ++c) arp = fmaf(ap[c], zx[c], arp);
    float Snode = 1.5f * quadsum(arp);

    int a0i = startA[n];
    int cn = cntA[n];                  // >= 1 (self loop)
    int nb = (cn + 3) >> 2;

    // pipeline prologue (colA gaps + tail pad are zeroed -> stray reads hit
    // node 0, masked out by wg)
    unsigned off0 = colB[a0i + e];
    float al0 = *(const float*)(alb + ((off0 >> 4) & ~15u) + h4);
    int4 d0 = *(const int4*)(xlb + off0 + hq16);
    unsigned off1 = off0;
    if (nb > 1) off1 = colB[a0i + 4 + e];

    float acc[8] = {0.f,0.f,0.f,0.f,0.f,0.f,0.f,0.f};
    float wsum = 0.f;

    for (int b = 0; b < nb; ++b) {
        unsigned off2 = off1;
        if (b + 2 < nb) off2 = colB[a0i + (b + 2) * 4 + e];
        float al1 = al0; int4 d1 = d0;
        if (b + 1 < nb) {
            al1 = *(const float*)(alb + ((off1 >> 4) & ~15u) + h4);
            d1 = *(const int4*)(xlb + off1 + hq16);
        }
        float z[8]; unpack8(d0, z);
        float t0 = z[0] + zx[0];
        float D = ap[0] * fabsf(t0);
#pragma unroll
        for (int c = 1; c < 8; ++c) {
            float tc = z[c] + zx[c];
            D = fmaf(ap[c], fabsf(tc), D);
        }
        D = quadsum(D);
        float wg = exp2f(al0 + Snode + D);
        if (b == nb - 1) wg = (b * 4 + e < cn) ? wg : 0.f;   // tail mask
#pragma unroll
        for (int c = 0; c < 8; ++c) acc[c] = fmaf(wg, z[c], acc[c]);
        wsum += wg;
        off0 = off1; off1 = off2; al0 = al1; d0 = d1;
    }

    // reduce across the 4 edge groups (lanes xor 16, 32)
#pragma unroll
    for (int c = 0; c < 8; ++c) {
        acc[c] += __shfl_xor(acc[c], 16, 64);
        acc[c] += __shfl_xor(acc[c], 32, 64);
    }
    wsum += __shfl_xor(wsum, 16, 64);
    wsum += __shfl_xor(wsum, 32, 64);

    float inv = 1.f / wsum;
    float4 b0 = *(const float4*)&bias[hq * 8];
    float4 b1 = *(const float4*)&bias[hq * 8 + 4];
    float bv[8] = {b0.x,b0.y,b0.z,b0.w,b1.x,b1.y,b1.z,b1.w};
    unsigned r[4];
#pragma unroll
    for (int k = 0; k < 4; ++k) {
        float o0 = fmaf(acc[2*k],     inv, bv[2*k]);
        float o1 = fmaf(acc[2*k + 1], inv, bv[2*k + 1]);
        r[k] = (unsigned)f2b(o0) | ((unsigned)f2b(o1) << 16);
    }
    if (lane < 16)
        *(int4*)((char*)hout + (size_t)n * 256 + hq16) = *(int4*)r;
}

// ================= BatchNorm stats (bf16 h) + finalize =======================
__global__ __launch_bounds__(256) void k_bnstats(const unsigned* __restrict__ h,
                                                 float* __restrict__ gsum,
                                                 float* __restrict__ gsq) {
    int t = threadIdx.x;
    int col = t & 63;
    int wv = t >> 6;
    float s0 = 0.f, s1 = 0.f, q0 = 0.f, q1 = 0.f;
    for (int r = blockIdx.x * 4 + wv; r < N_NODES; r += 512 * 4) {
        unsigned u = h[(size_t)r * 64 + col];
        float v0 = __uint_as_float(u << 16);
        float v1 = __uint_as_float(u & 0xFFFF0000u);
        s0 += v0; q0 = fmaf(v0, v0, q0);
        s1 += v1; q1 = fmaf(v1, v1, q1);
    }
    __shared__ float2 sS[4][64], sQ[4][64];
    sS[wv][col] = make_float2(s0, s1);
    sQ[wv][col] = make_float2(q0, q1);
    __syncthreads();
    if (t < 64) {
        float2 a0 = sS[0][t], a1 = sS[1][t], a2 = sS[2][t], a3 = sS[3][t];
        float2 b0 = sQ[0][t], b1 = sQ[1][t], b2 = sQ[2][t], b3 = sQ[3][t];
        atomicAdd(&gsum[2 * t],     a0.x + a1.x + a2.x + a3.x);
        atomicAdd(&gsum[2 * t + 1], a0.y + a1.y + a2.y + a3.y);
        atomicAdd(&gsq[2 * t],      b0.x + b1.x + b2.x + b3.x);
        atomicAdd(&gsq[2 * t + 1],  b0.y + b1.y + b2.y + b3.y);
    }
}

__global__ void k_bnfinal(const float* __restrict__ gsum, const float* __restrict__ gsq,
                          const float* __restrict__ g, const float* __restrict__ be,
                          float* __restrict__ sc, float* __restrict__ sh) {
    int c = threadIdx.x;   // 128
    float mu = gsum[c] * (1.f / N_NODES);
    float var = gsq[c] * (1.f / N_NODES) - mu * mu;
    float s = rsqrtf(var + EPS_BN) * g[c];
    sc[c] = s;
    sh[c] = be[c] - mu * s;
}

// ================= graph boundaries (batch is sorted) ========================
__global__ void k_gstart(const int* __restrict__ batch, int* __restrict__ gstart) {
    int i = blockIdx.x * 256 + threadIdx.x;
    if (i >= N_NODES) return;
    int b = batch[i];
    int prev = (i == 0) ? -1 : batch[i - 1];
    for (int g = prev + 1; g <= b; g++) gstart[g] = i;
    if (i == N_NODES - 1)
        for (int g = b + 1; g <= NG; g++) gstart[g] = N_NODES;
}

// ====== mean pool over bf16 h (fused BN2 affine+relu) + concat global =======
__global__ __launch_bounds__(256) void k_pool(const unsigned* __restrict__ h,
                                              const int* __restrict__ gstart,
                                              const float* __restrict__ gf,
                                              const float* __restrict__ sc,
                                              const float* __restrict__ sh,
                                              float* __restrict__ z) {
    int wave = threadIdx.x >> 6;
    int lane = threadIdx.x & 63;
    int g = blockIdx.x * 4 + wave;
    if (g >= NG) return;
    int c0 = lane * 2;
    float sc0 = sc[c0], sc1 = sc[c0 + 1], sh0 = sh[c0], sh1 = sh[c0 + 1];
    int r0 = gstart[g], r1 = gstart[g + 1];
    float s0 = 0.f, s1 = 0.f;
    for (int r = r0; r < r1; r++) {
        unsigned u = h[(size_t)r * 64 + lane];
        float v0 = __uint_as_float(u << 16);
        float v1 = __uint_as_float(u & 0xFFFF0000u);
        s0 += fmaxf(fmaf(v0, sc0, sh0), 0.f);
        s1 += fmaxf(fmaf(v1, sc1, sh1), 0.f);
    }
    float invc = 1.f / fmaxf((float)(r1 - r0), 1.f);
    float2 o; o.x = s0 * invc; o.y = s1 * invc;
    *(float2*)&z[(size_t)g * 160 + c0] = o;
    if (lane < 16) {
        float2 gv = *(const float2*)&gf[(size_t)g * 32 + lane * 2];
        *(float2*)&z[(size_t)g * 160 + 128 + lane * 2] = gv;
    }
}

// ================= MLP head ==================================================
__global__ __launch_bounds__(256) void k_mlp(const float* __restrict__ z,
                                             const float* __restrict__ W1,
                                             const float* __restrict__ b1,
                                             const float* __restrict__ W2,
                                             const float* __restrict__ b2,
                                             float* __restrict__ out) {
    __shared__ float zs[160];
    __shared__ float red[4];
    int g = blockIdx.x;
    int t = threadIdx.x;
    if (t < 160) zs[t] = z[(size_t)g * 160 + t];
    __syncthreads();
    float acc = b1[t];
#pragma unroll 8
    for (int i = 0; i < 160; i++) acc = fmaf(zs[i], W1[i * 256 + t], acc);
    acc = fmaxf(acc, 0.f);
    float part = acc * W2[t];
    part += __shfl_xor(part, 32, 64);
    part += __shfl_xor(part, 16, 64);
    part += __shfl_xor(part, 8, 64);
    part += __shfl_xor(part, 4, 64);
    part += __shfl_xor(part, 2, 64);
    part += __shfl_xor(part, 1, 64);
    if ((t & 63) == 0) red[t >> 6] = part;
    __syncthreads();
    if (t == 0) out[g] = red[0] + red[1] + red[2] + red[3] + b2[0];
}

extern "C" void kernel_launch(void* const* d_in, const int* in_sizes, int n_in,
                              void* d_out, int out_size, void* d_ws, size_t ws_size,
                              hipStream_t stream) {
    (void)in_sizes; (void)n_in; (void)out_size; (void)ws_size;

    const float* x     = (const float*)d_in[0];
    const int*   ei    = (const int*)d_in[1];
    const int*   batch = (const int*)d_in[2];
    const float* gf    = (const float*)d_in[3];
    const float* Wl1 = (const float*)d_in[4];
    const float* bl1 = (const float*)d_in[5];
    const float* Wr1 = (const float*)d_in[6];
    const float* br1 = (const float*)d_in[7];
    const float* att1  = (const float*)d_in[8];
    const float* bias1 = (const float*)d_in[9];
    const float* g1  = (const float*)d_in[10];
    const float* be1 = (const float*)d_in[11];
    const float* Wl2 = (const float*)d_in[12];
    const float* bl2 = (const float*)d_in[13];
    const float* Wr2 = (const float*)d_in[14];
    const float* br2 = (const float*)d_in[15];
    const float* att2  = (const float*)d_in[16];
    const float* bias2 = (const float*)d_in[17];
    const float* g2  = (const float*)d_in[18];
    const float* be2 = (const float*)d_in[19];
    const float* Wfc1 = (const float*)d_in[20];
    const float* bfc1 = (const float*)d_in[21];
    const float* Wfc2 = (const float*)d_in[22];
    const float* bfc2 = (const float*)d_in[23];
    float* out = (float*)d_out;

    char* ws = (char*)d_ws;
    unsigned short* xl = (unsigned short*)(ws + 0);            // 25.6 MB bf16
    unsigned short* xr = (unsigned short*)(ws + 25600000);     // 25.6 MB bf16
    unsigned* h     = (unsigned*)(ws + 51200000);              // 25.6 MB bf16 packed
    int*   colA     = (int*)(ws + 76800000);                   // 9.63 MB + 256 pad (zeroed)
    int*   bktBuf   = (int*)(ws + 86434560);                   // 9.63 MB packed ints
    int*   bucketCur= (int*)(ws + 96068608);                   // 1 KB   } zeroed
    float* bnsum    = (float*)(ws + 96069632);                 // 2 KB   } together
    int*   cntA     = (int*)(ws + 96071680);                   // 400 KB
    int*   startA   = (int*)(ws + 96471680);                   // 400 KB
    float* scsh     = (float*)(ws + 96871680);                 // sc1|sh1|sc2|sh2
    int*   gstart   = (int*)(ws + 96873728);                   // 4.1 KB
    float* z        = (float*)(ws + 96878080);                 // 655 KB
    unsigned short* Wimg = (unsigned short*)(ws + 97533440);   // 64 KB
    float* Al       = (float*)(ws + 97598976);                 // 1.6 MB [N][4]

    // zero: colA incl. tail pad (stray pipeline reads -> node 0, masked),
    // bucketCur + bnsum (contiguous)
    hipMemsetAsync(colA, 0, NB * BCAP * 4 + 256, stream);
    hipMemsetAsync(bucketCur, 0, 1024 + 2048, stream);

    // CSR build (shared by both layers) + graph boundaries
    k_part<<<(EP + 4095) / 4096, 256, 0, stream>>>(ei, bucketCur, bktBuf);
    k_gstart<<<(N_NODES + 255) / 256, 256, 0, stream>>>(batch, gstart);
    k_build<<<NB, 512, 0, stream>>>(bktBuf, bucketCur, startA, cntA, colA);

    int gemm_grid = (N_NODES + 63) / 64;

    // Layer 1
    k_wconv<<<16, 256, 0, stream>>>(Wl1, Wr1, Wimg);
    k_gemm<false, false><<<gemm_grid, 256, 0, stream>>>(x, Wimg, bl1, br1,
                                                        nullptr, nullptr, att1, Al,
                                                        xl, xr, N_NODES);
    k_agg<<<N_NODES / 4, 256, 0, stream>>>((const unsigned*)xl, (const unsigned*)xr,
                                           startA, cntA, (const unsigned*)colA,
                                           att1, bias1, Al, h);
    k_bnstats<<<512, 256, 0, stream>>>(h, bnsum + 0, bnsum + 128);
    k_bnfinal<<<1, 128, 0, stream>>>(bnsum + 0, bnsum + 128, g1, be1, scsh + 0, scsh + 128);

    // Layer 2 (BN1 apply + ReLU fused into GEMM A-staging, bf16 input)
    k_wconv<<<16, 256, 0, stream>>>(Wl2, Wr2, Wimg);
    k_gemm<true, true><<<gemm_grid, 256, 0, stream>>>(h, Wimg, bl2, br2,
                                                      scsh + 0, scsh + 128, att2, Al,
                                                      xl, xr, N_NODES);
    k_agg<<<N_NODES / 4, 256, 0, stream>>>((const unsigned*)xl, (const unsigned*)xr,
                                           startA, cntA, (const unsigned*)colA,
                                           att2, bias2, Al, h);
    k_bnstats<<<512, 256, 0, stream>>>(h, bnsum + 256, bnsum + 384);
    k_bnfinal<<<1, 128, 0, stream>>>(bnsum + 256, bnsum + 384, g2, be2, scsh + 256, scsh + 384);

    // Pool (BN2 apply + ReLU fused) + MLP
    k_pool<<<(NG + 3) / 4, 256, 0, stream>>>(h, gstart, gf, scsh + 256, scsh + 384, z);
    k_mlp<<<NG, 256, 0, stream>>>(z, Wfc1, bfc1, Wfc2, bfc2, out);
}

// Round 12
// 343.066 us; speedup vs baseline: 1.2383x; 1.1839x over previous
//
#include <hip/hip_runtime.h>

#define N_NODES 100000
#define E_EDGES 1600000
#define EP (E_EDGES + N_NODES)
#define NG 1024
#define NEG 0.2f
#define EPS_BN 1e-5f
#define LOG2E 1.44269504088896f

#define NB 196        // dst buckets of 512 nodes
#define BCAP 12288    // per-bucket capacity (mean 8704)

typedef __attribute__((ext_vector_type(8))) short bf8_t;
typedef __attribute__((ext_vector_type(4))) float f4_t;

__device__ __forceinline__ unsigned short f2b(float f) {   // f32 -> bf16 RNE
    unsigned u = __float_as_uint(f);
    u += 0x7FFF + ((u >> 16) & 1);
    return (unsigned short)(u >> 16);
}

// 16-lane sum via mov_dpp row_ror butterfly; result broadcast to 16 lanes.
__device__ __forceinline__ float rsum16(float p) {
    p += __int_as_float(__builtin_amdgcn_mov_dpp(__float_as_int(p), 0x128, 0xf, 0xf, true));
    p += __int_as_float(__builtin_amdgcn_mov_dpp(__float_as_int(p), 0x124, 0xf, 0xf, true));
    p += __int_as_float(__builtin_amdgcn_mov_dpp(__float_as_int(p), 0x122, 0xf, 0xf, true));
    p += __int_as_float(__builtin_amdgcn_mov_dpp(__float_as_int(p), 0x121, 0xf, 0xf, true));
    return p;
}

// 4-lane (quad) sum via quad_perm DPP; result broadcast to all 4 lanes.
__device__ __forceinline__ float quadsum(float p) {
    p += __int_as_float(__builtin_amdgcn_mov_dpp(__float_as_int(p), 0xB1, 0xf, 0xf, true)); // [1,0,3,2]
    p += __int_as_float(__builtin_amdgcn_mov_dpp(__float_as_int(p), 0x4E, 0xf, 0xf, true)); // [2,3,0,1]
    return p;
}

__device__ __forceinline__ void unpack8(const int4& d, float* z) {
    unsigned a = (unsigned)d.x, b = (unsigned)d.y, c = (unsigned)d.z, w = (unsigned)d.w;
    z[0] = __uint_as_float(a << 16); z[1] = __uint_as_float(a & 0xFFFF0000u);
    z[2] = __uint_as_float(b << 16); z[3] = __uint_as_float(b & 0xFFFF0000u);
    z[4] = __uint_as_float(c << 16); z[5] = __uint_as_float(c & 0xFFFF0000u);
    z[6] = __uint_as_float(w << 16); z[7] = __uint_as_float(w & 0xFFFF0000u);
}

// ================= CSR build: partition -> per-bucket build (packed int) =====
// buf entry = (src << 9) | (dst & 511); bucket = dst >> 9.
__global__ __launch_bounds__(256) void k_part(const int* __restrict__ ei,
                                              int* __restrict__ bucketCur,
                                              int* __restrict__ buf) {
    __shared__ int lh[NB], lb[NB];
    int t = threadIdx.x;
    for (int i = t; i < NB; i += 256) lh[i] = 0;
    __syncthreads();
    int base = blockIdx.x * 4096;
    int pk[16];
    int bk[16];
    int rk[16];
#pragma unroll
    for (int i = 0; i < 16; i++) {
        int idx = base + i * 256 + t;
        int s, d;
        if (idx < E_EDGES) { s = ei[idx]; d = ei[E_EDGES + idx]; }
        else if (idx < EP) { s = d = idx - E_EDGES; }
        else { s = 0; d = -1; }
        pk[i] = (s << 9) | (d & 511);
        bk[i] = d >> 9;
        rk[i] = (d >= 0) ? atomicAdd(&lh[d >> 9], 1) : 0;
    }
    __syncthreads();
    for (int i = t; i < NB; i += 256) lb[i] = atomicAdd(&bucketCur[i], lh[i]);
    __syncthreads();
#pragma unroll
    for (int i = 0; i < 16; i++) {
        int bkt = bk[i];
        if (bkt >= 0)
            buf[(size_t)bkt * BCAP + lb[bkt] + rk[i]] = pk[i];
    }
}

// per-bucket: histogram -> LDS scan -> startA/cntA -> place colA (byte offsets)
// + zero a 16-int tail pad after each bucket's used region (pipeline over-reads)
__global__ __launch_bounds__(512) void k_build(const int* __restrict__ buf,
                                               const int* __restrict__ bcnt,
                                               int* __restrict__ startA,
                                               int* __restrict__ cntA,
                                               int* __restrict__ colA) {
    __shared__ int h[512];
    __shared__ int s[512];
    int b = blockIdx.x, t = threadIdx.x;
    h[t] = 0;
    __syncthreads();
    int n = bcnt[b];
    const int* p = buf + (size_t)b * BCAP;
    for (int i = t; i < n; i += 512) atomicAdd(&h[p[i] & 511], 1);
    __syncthreads();
    int v = h[t];
    s[t] = v;
    __syncthreads();
    for (int o = 1; o < 512; o <<= 1) {
        int u = (t >= o) ? s[t - o] : 0;
        __syncthreads();
        s[t] += u;
        __syncthreads();
    }
    int myStart = b * BCAP + s[t] - v;   // exclusive prefix within bucket
    int node = (b << 9) + t;
    if (node < N_NODES) {
        startA[node] = myStart;
        cntA[node] = v;
    }
    h[t] = myStart;                      // reuse as running cursor
    __syncthreads();
    for (int i = t; i < n; i += 512) {
        int e = p[i];
        int r = atomicAdd(&h[e & 511], 1);
        colA[r] = (e >> 9) << 8;         // src * 256 (byte offset into xl)
    }
    if (t < 16) colA[b * BCAP + n + t] = 0;   // tail pad (stray reads -> node 0)
}

// ========== prep: wconv L1+L2 (blocks 0..31) + gstart (blocks 32..) ==========
__global__ __launch_bounds__(256) void k_prep(
    const float* __restrict__ Wl1, const float* __restrict__ Wr1,
    const float* __restrict__ Wl2, const float* __restrict__ Wr2,
    unsigned short* __restrict__ img1, unsigned short* __restrict__ img2,
    const int* __restrict__ batch, int* __restrict__ gstart) {
    int blk = blockIdx.x;
    if (blk < 32) {
        int lay = blk >> 4;
        int g = (blk & 15) * 256 + threadIdx.x;   // 4096 chunks per layer
        int m = g >> 11, n = (g >> 4) & 127, kb = g & 15;
        const float* W = lay ? (m ? Wr2 : Wl2) : (m ? Wr1 : Wl1);
        unsigned short* img = lay ? img2 : img1;
        unsigned short v[8];
#pragma unroll
        for (int j = 0; j < 8; j++) v[j] = f2b(W[(kb * 8 + j) * 128 + n]);
        int off = m * 32768 + n * 256 + kb * 16;
        *(int4*)((char*)img + off) = *(int4*)v;
    } else {
        int i = (blk - 32) * 256 + threadIdx.x;
        if (i >= N_NODES) return;
        int b = batch[i];
        int prev = (i == 0) ? -1 : batch[i - 1];
        for (int g = prev + 1; g <= b; g++) gstart[g] = i;
        if (i == N_NODES - 1)
            for (int g = b + 1; g <= NG; g++) gstart[g] = N_NODES;
    }
}

// ================= MFMA dual GEMM: xl = A@Wl + bl, xr = A@Wr + br (bf16) =====
// W fragments straight from global (L2-hot). Fused epilogue also emits
// Al[n][h] = 0.6*log2e * att_h . xl[n]  (from f32 accumulators, mat=0 waves).
template<bool AFF, bool BF16IN>
__global__ __launch_bounds__(256) void k_gemm(
    const void* __restrict__ Ain, const unsigned short* __restrict__ Wimg,
    const float* __restrict__ bl, const float* __restrict__ br,
    const float* __restrict__ sc, const float* __restrict__ sh,
    const float* __restrict__ att, float* __restrict__ Al,
    unsigned short* __restrict__ xl, unsigned short* __restrict__ xr, int M)
{
    __shared__ char lds[32768];
    short* As = (short*)lds;             // 16384 B

    int t = threadIdx.x;
    int lane = t & 63;
    int w = t >> 6;
    int brow = blockIdx.x * 64;

    int rl = lane & 15;
    int kh = lane >> 4;
    int mat = w >> 1;
    int c0 = (w & 1) * 64;

    // ---- B fragments from global (issued first, overlap with A staging) ----
    const char* wbase = (const char*)Wimg + mat * 32768;
    bf8_t bfr[4][4];
#pragma unroll
    for (int s = 0; s < 4; ++s)
#pragma unroll
        for (int j = 0; j < 4; ++j)
            bfr[s][j] = *(const bf8_t*)(wbase + (c0 + 16 * j + rl) * 256 + s * 64 + kh * 16);

    // ---- stage A (f32 or packed-bf16 input; optional BN-affine+relu) ----
    {
        int kbase = (t & 7) * 16;
        float scv[16], shv[16];
        if (AFF) {
#pragma unroll
            for (int q = 0; q < 4; ++q) {
                float4 a4 = *(const float4*)&sc[kbase + q * 4];
                float4 b4 = *(const float4*)&sh[kbase + q * 4];
                scv[q*4+0]=a4.x; scv[q*4+1]=a4.y; scv[q*4+2]=a4.z; scv[q*4+3]=a4.w;
                shv[q*4+0]=b4.x; shv[q*4+1]=b4.y; shv[q*4+2]=b4.z; shv[q*4+3]=b4.w;
            }
        }
#pragma unroll
        for (int p = 0; p < 2; ++p) {
            int row = p * 32 + (t >> 3);
            int ar = brow + row; if (ar >= M) ar = M - 1;
            unsigned short vb[16];
            if (BF16IN) {
                const unsigned* src = (const unsigned*)Ain + (size_t)ar * 64 + (kbase >> 1);
                int4 r0 = *(const int4*)src;
                int4 r1 = *(const int4*)(src + 4);
                unsigned ua[8] = {(unsigned)r0.x,(unsigned)r0.y,(unsigned)r0.z,(unsigned)r0.w,
                                  (unsigned)r1.x,(unsigned)r1.y,(unsigned)r1.z,(unsigned)r1.w};
#pragma unroll
                for (int m = 0; m < 8; ++m) {
                    float f0 = __uint_as_float(ua[m] << 16);
                    float f1 = __uint_as_float(ua[m] & 0xFFFF0000u);
                    if (AFF) {
                        f0 = fmaxf(fmaf(f0, scv[2*m], shv[2*m]), 0.f);
                        f1 = fmaxf(fmaf(f1, scv[2*m+1], shv[2*m+1]), 0.f);
                    }
                    vb[2*m] = f2b(f0); vb[2*m+1] = f2b(f1);
                }
            } else {
                const float* src = (const float*)Ain + (size_t)ar * 128 + kbase;
#pragma unroll
                for (int q = 0; q < 4; ++q) {
                    float4 x4 = *(const float4*)&src[q * 4];
                    float vv[4] = {x4.x, x4.y, x4.z, x4.w};
#pragma unroll
                    for (int e = 0; e < 4; ++e) {
                        float f = vv[e];
                        if (AFF) f = fmaxf(fmaf(f, scv[q*4+e], shv[q*4+e]), 0.f);
                        vb[q * 4 + e] = f2b(f);
                    }
                }
            }
            int swz = (row & 7) << 4;
#pragma unroll
            for (int u = 0; u < 2; ++u) {
                int off = (row * 256 + kbase * 2 + u * 16) ^ swz;
                *(int4*)((char*)As + off) = *(int4*)&vb[u * 8];
            }
        }
    }
    __syncthreads();

    // ---- compute ----
    int swz = (rl & 7) << 4;
    f4_t acc[4][4];
#pragma unroll
    for (int i = 0; i < 4; ++i)
#pragma unroll
        for (int j = 0; j < 4; ++j) { f4_t z = {0.f,0.f,0.f,0.f}; acc[i][j] = z; }

    const char* Asc = (const char*)As;
#pragma unroll
    for (int s = 0; s < 4; ++s) {
        int kb2 = (s * 32 + kh * 8) * 2;
        bf8_t af[4];
#pragma unroll
        for (int i = 0; i < 4; ++i) {
            int row = 16 * i + rl;
            af[i] = *(const bf8_t*)(Asc + ((row * 256 + kb2) ^ swz));
        }
#pragma unroll
        for (int i = 0; i < 4; ++i)
#pragma unroll
            for (int j = 0; j < 4; ++j)
                acc[i][j] = __builtin_amdgcn_mfma_f32_16x16x32_bf16(af[i], bfr[s][j], acc[i][j], 0, 0, 0);
    }

    // ---- epilogue ----
    __syncthreads();
    short* Cs = (short*)lds;   // [64][256] bf16, swizzled (32 KB)
    const float* bb = mat ? br : bl;
    float blv[4];
#pragma unroll
    for (int j = 0; j < 4; ++j) blv[j] = bb[c0 + 16 * j + rl];

    // fused Al (source-logit) for xl waves: per-head 32-ch dot via rsum16.
    if (mat == 0) {
        const float sAl = 0.6f * LOG2E;
        float ap0 = att[c0 + rl] * sAl;
        float ap1 = att[c0 + 16 + rl] * sAl;
        float ap2 = att[c0 + 32 + rl] * sAl;
        float ap3 = att[c0 + 48 + rl] * sAl;
        float cl = fmaf(ap0, blv[0], ap1 * blv[1]);
        float ch = fmaf(ap2, blv[2], ap3 * blv[3]);
        int hbase = c0 >> 5;   // 0 (w=0) or 2 (w=1)
#pragma unroll
        for (int i = 0; i < 4; ++i)
#pragma unroll
            for (int q = 0; q < 4; ++q) {
                float pl = fmaf(ap0, acc[i][0][q], fmaf(ap1, acc[i][1][q], cl));
                float ph = fmaf(ap2, acc[i][2][q], fmaf(ap3, acc[i][3][q], ch));
                pl = rsum16(pl);
                ph = rsum16(ph);
                int node = brow + 16 * i + kh * 4 + q;
                if (rl == 0 && node < M) {
                    float2 w2 = make_float2(pl, ph);
                    *(float2*)&Al[(size_t)node * 4 + hbase] = w2;
                }
            }
    }

#pragma unroll
    for (int i = 0; i < 4; ++i)
#pragma unroll
        for (int j = 0; j < 4; ++j) {
            int col = mat * 128 + c0 + 16 * j + rl;
#pragma unroll
            for (int q = 0; q < 4; ++q) {
                int row = 16 * i + kh * 4 + q;
                int off = (row * 512 + col * 2) ^ ((row & 7) << 4);
                *(short*)((char*)Cs + off) = (short)f2b(acc[i][j][q] + blv[j]);
            }
        }
    __syncthreads();
#pragma unroll
    for (int rep = 0; rep < 8; ++rep) {
        int unit = rep * 256 + t;
        int row = unit >> 5;
        int slot = unit & 31;
        int gr = brow + row;
        if (gr < M) {
            int off = (row * 512 + slot * 16) ^ ((row & 7) << 4);
            int4 vv = *(const int4*)((char*)Cs + off);
            unsigned short* O = (slot < 16) ? xl : xr;
            int gcol = (slot & 15) * 8;
            *(int4*)&O[(size_t)gr * 128 + gcol] = vv;
        }
    }
}

// ===== fused edge softmax + aggregation + BN stats, lane = (edge,head,qtr) ===
// round-7 edge loop (unchanged); epilogue adds 4-wave LDS reduce of per-node
// output sums/sumsqs -> 64-way-spread partial buffers (atomics, low contention).
__global__ __launch_bounds__(256) void k_agg(
    const unsigned* __restrict__ xl, const unsigned* __restrict__ xr,
    const int* __restrict__ startA, const int* __restrict__ cntA,
    const unsigned* __restrict__ colB,
    const float* __restrict__ att, const float* __restrict__ bias,
    const float* __restrict__ Al, unsigned* __restrict__ hout,
    float* __restrict__ SP)
{
    int tid = threadIdx.x;
    int lane = tid & 63;
    int wv = tid >> 6;
    int n = blockIdx.x * 4 + wv;
    int e = lane >> 4;                 // edge slot 0..3
    int hq = lane & 15;                // h*4+q
    int h4 = (hq >> 2) * 4;            // byte offset of head in Al row
    unsigned hq16 = (unsigned)hq * 16u;
    const char* xlb = (const char*)xl;
    const char* alb = (const char*)Al;

    // att' slice (8 ch of this head-quarter), pre-scaled by 0.4*log2e
    float ap[8];
    {
        float4 q0 = *(const float4*)&att[hq * 8];
        float4 q1 = *(const float4*)&att[hq * 8 + 4];
        const float s = 0.4f * LOG2E;
        ap[0]=q0.x*s; ap[1]=q0.y*s; ap[2]=q0.z*s; ap[3]=q0.w*s;
        ap[4]=q1.x*s; ap[5]=q1.y*s; ap[6]=q1.z*s; ap[7]=q1.w*s;
    }
    // xr slice for this node
    float zx[8];
    {
        int4 xru = *(const int4*)((const char*)xr + (size_t)n * 256 + hq16);
        unpack8(xru, zx);
    }
    // Snode = 0.6*log2e * att_h . xr[n]  (= 1.5 * quadsum(dot(ap, zx)))
    float arp = ap[0] * zx[0];
#pragma unroll
    for (int c = 1; c < 8; ++c) arp = fmaf(ap[c], zx[c], arp);
    float Snode = 1.5f * quadsum(arp);

    int a0i = startA[n];
    int cn = cntA[n];                  // >= 1 (self loop)
    int nb = (cn + 3) >> 2;

    // pipeline prologue (bucket tail pads zeroed -> stray reads hit node 0,
    // masked out by wg)
    unsigned off0 = colB[a0i + e];
    float al0 = *(const float*)(alb + ((off0 >> 4) & ~15u) + h4);
    int4 d0 = *(const int4*)(xlb + off0 + hq16);
    unsigned off1 = off0;
    if (nb > 1) off1 = colB[a0i + 4 + e];

    float acc[8] = {0.f,0.f,0.f,0.f,0.f,0.f,0.f,0.f};
    float wsum = 0.f;

    for (int b = 0; b < nb; ++b) {
        unsigned off2 = off1;
        if (b + 2 < nb) off2 = colB[a0i + (b + 2) * 4 + e];
        float al1 = al0; int4 d1 = d0;
        if (b + 1 < nb) {
            al1 = *(const float*)(alb + ((off1 >> 4) & ~15u) + h4);
            d1 = *(const int4*)(xlb + off1 + hq16);
        }
        float z[8]; unpack8(d0, z);
        float t0 = z[0] + zx[0];
        float D = ap[0] * fabsf(t0);
#pragma unroll
        for (int c = 1; c < 8; ++c) {
            float tc = z[c] + zx[c];
            D = fmaf(ap[c], fabsf(tc), D);
        }
        D = quadsum(D);
        float wg = exp2f(al0 + Snode + D);
        if (b == nb - 1) wg = (b * 4 + e < cn) ? wg : 0.f;   // tail mask
#pragma unroll
        for (int c = 0; c < 8; ++c) acc[c] = fmaf(wg, z[c], acc[c]);
        wsum += wg;
        off0 = off1; off1 = off2; al0 = al1; d0 = d1;
    }

    // reduce across the 4 edge groups (lanes xor 16, 32)
#pragma unroll
    for (int c = 0; c < 8; ++c) {
        acc[c] += __shfl_xor(acc[c], 16, 64);
        acc[c] += __shfl_xor(acc[c], 32, 64);
    }
    wsum += __shfl_xor(wsum, 16, 64);
    wsum += __shfl_xor(wsum, 32, 64);

    float inv = 1.f / wsum;
    float4 b0 = *(const float4*)&bias[hq * 8];
    float4 b1 = *(const float4*)&bias[hq * 8 + 4];
    float bv[8] = {b0.x,b0.y,b0.z,b0.w,b1.x,b1.y,b1.z,b1.w};
    float ov[8];
    unsigned r[4];
#pragma unroll
    for (int k = 0; k < 4; ++k) {
        float o0 = fmaf(acc[2*k],     inv, bv[2*k]);
        float o1 = fmaf(acc[2*k + 1], inv, bv[2*k + 1]);
        ov[2*k] = o0; ov[2*k+1] = o1;
        r[k] = (unsigned)f2b(o0) | ((unsigned)f2b(o1) << 16);
    }

    // BN stats: per-node (lane<16 holds the 128 channels, 8 each)
    __shared__ float sO[4][128], sQ[4][128];
    if (lane < 16) {
        *(int4*)((char*)hout + (size_t)n * 256 + hq16) = *(int4*)r;
#pragma unroll
        for (int c = 0; c < 8; ++c) {
            sO[wv][hq * 8 + c] = ov[c];
            sQ[wv][hq * 8 + c] = ov[c] * ov[c];
        }
    }
    __syncthreads();
    if (tid < 128) {
        float s = sO[0][tid] + sO[1][tid] + sO[2][tid] + sO[3][tid];
        float q = sQ[0][tid] + sQ[1][tid] + sQ[2][tid] + sQ[3][tid];
        float* slot = SP + (size_t)(blockIdx.x & 63) * 256;
        atomicAdd(&slot[tid], s);
        atomicAdd(&slot[128 + tid], q);
    }
}

// ================= BN finalize: reduce 64 partials -> scsh, re-zero =========
__global__ void k_bnfinal(float* __restrict__ SP,
                          const float* __restrict__ g, const float* __restrict__ be,
                          float* __restrict__ sc, float* __restrict__ sh) {
    int c = threadIdx.x;   // 128
    float s = 0.f, q = 0.f;
    for (int j = 0; j < 64; ++j) {
        s += SP[j * 256 + c];
        q += SP[j * 256 + 128 + c];
    }
    float mu = s * (1.f / N_NODES);
    float var = q * (1.f / N_NODES) - mu * mu;
    float sv = rsqrtf(var + EPS_BN) * g[c];
    sc[c] = sv;
    sh[c] = be[c] - mu * sv;
    for (int j = 0; j < 64; ++j) {        // re-zero for the next layer/replay
        SP[j * 256 + c] = 0.f;
        SP[j * 256 + 128 + c] = 0.f;
    }
}

// ====== mean pool over bf16 h (fused BN2 affine+relu) + concat global =======
__global__ __launch_bounds__(256) void k_pool(const unsigned* __restrict__ h,
                                              const int* __restrict__ gstart,
                                              const float* __restrict__ gf,
                                              const float* __restrict__ sc,
                                              const float* __restrict__ sh,
                                              float* __restrict__ z) {
    int wave = threadIdx.x >> 6;
    int lane = threadIdx.x & 63;
    int g = blockIdx.x * 4 + wave;
    if (g >= NG) return;
    int c0 = lane * 2;
    float sc0 = sc[c0], sc1 = sc[c0 + 1], sh0 = sh[c0], sh1 = sh[c0 + 1];
    int r0 = gstart[g], r1 = gstart[g + 1];
    float s0 = 0.f, s1 = 0.f;
    for (int r = r0; r < r1; r++) {
        unsigned u = h[(size_t)r * 64 + lane];
        float v0 = __uint_as_float(u << 16);
        float v1 = __uint_as_float(u & 0xFFFF0000u);
        s0 += fmaxf(fmaf(v0, sc0, sh0), 0.f);
        s1 += fmaxf(fmaf(v1, sc1, sh1), 0.f);
    }
    float invc = 1.f / fmaxf((float)(r1 - r0), 1.f);
    float2 o; o.x = s0 * invc; o.y = s1 * invc;
    *(float2*)&z[(size_t)g * 160 + c0] = o;
    if (lane < 16) {
        float2 gv = *(const float2*)&gf[(size_t)g * 32 + lane * 2];
        *(float2*)&z[(size_t)g * 160 + 128 + lane * 2] = gv;
    }
}

// ================= MLP head ==================================================
__global__ __launch_bounds__(256) void k_mlp(const float* __restrict__ z,
                                             const float* __restrict__ W1,
                                             const float* __restrict__ b1,
                                             const float* __restrict__ W2,
                                             const float* __restrict__ b2,
                                             float* __restrict__ out) {
    __shared__ float zs[160];
    __shared__ float red[4];
    int g = blockIdx.x;
    int t = threadIdx.x;
    if (t < 160) zs[t] = z[(size_t)g * 160 + t];
    __syncthreads();
    float acc = b1[t];
#pragma unroll 8
    for (int i = 0; i < 160; i++) acc = fmaf(zs[i], W1[i * 256 + t], acc);
    acc = fmaxf(acc, 0.f);
    float part = acc * W2[t];
    part += __shfl_xor(part, 32, 64);
    part += __shfl_xor(part, 16, 64);
    part += __shfl_xor(part, 8, 64);
    part += __shfl_xor(part, 4, 64);
    part += __shfl_xor(part, 2, 64);
    part += __shfl_xor(part, 1, 64);
    if ((t & 63) == 0) red[t >> 6] = part;
    __syncthreads();
    if (t == 0) out[g] = red[0] + red[1] + red[2] + red[3] + b2[0];
}

extern "C" void kernel_launch(void* const* d_in, const int* in_sizes, int n_in,
                              void* d_out, int out_size, void* d_ws, size_t ws_size,
                              hipStream_t stream) {
    (void)in_sizes; (void)n_in; (void)out_size; (void)ws_size;

    const float* x     = (const float*)d_in[0];
    const int*   ei    = (const int*)d_in[1];
    const int*   batch = (const int*)d_in[2];
    const float* gf    = (const float*)d_in[3];
    const float* Wl1 = (const float*)d_in[4];
    const float* bl1 = (const float*)d_in[5];
    const float* Wr1 = (const float*)d_in[6];
    const float* br1 = (const float*)d_in[7];
    const float* att1  = (const float*)d_in[8];
    const float* bias1 = (const float*)d_in[9];
    const float* g1  = (const float*)d_in[10];
    const float* be1 = (const float*)d_in[11];
    const float* Wl2 = (const float*)d_in[12];
    const float* bl2 = (const float*)d_in[13];
    const float* Wr2 = (const float*)d_in[14];
    const float* br2 = (const float*)d_in[15];
    const float* att2  = (const float*)d_in[16];
    const float* bias2 = (const float*)d_in[17];
    const float* g2  = (const float*)d_in[18];
    const float* be2 = (const float*)d_in[19];
    const float* Wfc1 = (const float*)d_in[20];
    const float* bfc1 = (const float*)d_in[21];
    const float* Wfc2 = (const float*)d_in[22];
    const float* bfc2 = (const float*)d_in[23];
    float* out = (float*)d_out;

    char* ws = (char*)d_ws;
    unsigned short* xl = (unsigned short*)(ws + 0);            // 25.6 MB bf16
    unsigned short* xr = (unsigned short*)(ws + 25600000);     // 25.6 MB bf16
    unsigned* h     = (unsigned*)(ws + 51200000);              // 25.6 MB bf16 packed
    int*   colA     = (int*)(ws + 76800000);                   // 9.63 MB (bucketed)
    int*   bktBuf   = (int*)(ws + 86434560);                   // 9.63 MB packed ints
    int*   bucketCur= (int*)(ws + 96068608);                   // 1 KB  } zeroed
    float* SP       = (float*)(ws + 96069632);                 // 64 KB } together
    int*   cntA     = (int*)(ws + 96135168);                   // 400 KB
    int*   startA   = (int*)(ws + 96535168);                   // 400 KB
    float* scsh     = (float*)(ws + 96935168);                 // 2 KB: sc1|sh1|sc2|sh2
    int*   gstart   = (int*)(ws + 96937216);                   // 4.1 KB
    float* z        = (float*)(ws + 96941568);                 // 655 KB
    unsigned short* Wimg1 = (unsigned short*)(ws + 97596928);  // 64 KB
    unsigned short* Wimg2 = (unsigned short*)(ws + 97662464);  // 64 KB
    float* Al       = (float*)(ws + 97728000);                 // 1.6 MB [N][4]

    // zero: bucketCur (1KB) + SP (64KB) — contiguous, one dispatch
    hipMemsetAsync(bucketCur, 0, 1024 + 65536, stream);

    // prep (W images both layers + graph boundaries) + CSR build
    k_prep<<<423, 256, 0, stream>>>(Wl1, Wr1, Wl2, Wr2, Wimg1, Wimg2, batch, gstart);
    k_part<<<(EP + 4095) / 4096, 256, 0, stream>>>(ei, bucketCur, bktBuf);
    k_build<<<NB, 512, 0, stream>>>(bktBuf, bucketCur, startA, cntA, colA);

    int gemm_grid = (N_NODES + 63) / 64;

    // Layer 1
    k_gemm<false, false><<<gemm_grid, 256, 0, stream>>>(x, Wimg1, bl1, br1,
                                                        nullptr, nullptr, att1, Al,
                                                        xl, xr, N_NODES);
    k_agg<<<N_NODES / 4, 256, 0, stream>>>((const unsigned*)xl, (const unsigned*)xr,
                                           startA, cntA, (const unsigned*)colA,
                                           att1, bias1, Al, h, SP);
    k_bnfinal<<<1, 128, 0, stream>>>(SP, g1, be1, scsh + 0, scsh + 128);

    // Layer 2 (BN1 apply + ReLU fused into GEMM A-staging, bf16 input)
    k_gemm<true, true><<<gemm_grid, 256, 0, stream>>>(h, Wimg2, bl2, br2,
                                                      scsh + 0, scsh + 128, att2, Al,
                                                      xl, xr, N_NODES);
    k_agg<<<N_NODES / 4, 256, 0, stream>>>((const unsigned*)xl, (const unsigned*)xr,
                                           startA, cntA, (const unsigned*)colA,
                                           att2, bias2, Al, h, SP);
    k_bnfinal<<<1, 128, 0, stream>>>(SP, g2, be2, scsh + 256, scsh + 384);

    // Pool (BN2 apply + ReLU fused) + MLP
    k_pool<<<(NG + 3) / 4, 256, 0, stream>>>(h, gstart, gf, scsh + 256, scsh + 384, z);
    k_mlp<<<NG, 256, 0, stream>>>(z, Wfc1, bfc1, Wfc2, bfc2, out);
}